// Round 10
// baseline (1148.193 us; speedup 1.0000x reference)
//
#include <hip/hip_runtime.h>
#include <hip/hip_bf16.h>
#include <hip/hip_fp16.h>

// ---- problem dims ----
#define BATCH 256
#define TSTEPS 250
#define INDIM 700
#define KPAD 704         // 700 padded to 704 (22 chunks of 32)
#define HID 512
#define HK 2048          // HID*BR
#define NOUT 20
#define NCHUNK 66        // 3 segments * 22 k-chunks of 32
#define FCH 10           // filter chunks
#define FCL 25           // filter chunk length

typedef __attribute__((ext_vector_type(8))) _Float16 f16x8;
typedef __attribute__((ext_vector_type(4))) _Float16 f16x4;
typedef __attribute__((ext_vector_type(4))) float f32x4;
typedef __attribute__((ext_vector_type(16))) float f32x16;

__device__ __forceinline__ float sigf(float x) { return 1.0f / (1.0f + expf(-x)); }

__device__ __forceinline__ void gload_lds16(const void* g, void* l) {
    __builtin_amdgcn_global_load_lds(
        (const __attribute__((address_space(1))) void*)g,
        (__attribute__((address_space(3))) void*)l, 16, 0, 0);
}

// ---------------------------------------------------------------------------
// Kernel 1a: split x chunk into fp16 hi/lo, chunk-local rows (b*tc+tt).
// ---------------------------------------------------------------------------
__global__ __launch_bounds__(192) void split_x(
    const float* __restrict__ x, _Float16* __restrict__ X0,
    _Float16* __restrict__ X1, int t0, int tc) {
    const int row = blockIdx.x;                 // 0 .. 256*tc-1
    const int b = row / tc, tt = row - b * tc;
    const float* xr = x + (size_t)(b * TSTEPS + t0 + tt) * INDIM;
    const int k = threadIdx.x * 4;
    if (k >= KPAD) return;
    float4 v = {0.f, 0.f, 0.f, 0.f};
    if (k < INDIM) v = *(const float4*)(xr + k);   // 700 % 4 == 0: full quads
    f16x4 h, l;
    h[0] = (_Float16)v.x; l[0] = (_Float16)(v.x - (float)h[0]);
    h[1] = (_Float16)v.y; l[1] = (_Float16)(v.y - (float)h[1]);
    h[2] = (_Float16)v.z; l[2] = (_Float16)(v.z - (float)h[2]);
    h[3] = (_Float16)v.w; l[3] = (_Float16)(v.w - (float)h[3]);
    *(f16x4*)(X0 + (size_t)row * KPAD + k) = h;
    *(f16x4*)(X1 + (size_t)row * KPAD + k) = l;
}

// ---------------------------------------------------------------------------
// Kernel 1b: W = w1*mask split into fp16 hi/lo (2048 x 704, zero-padded).
// ---------------------------------------------------------------------------
__global__ __launch_bounds__(192) void split_w(
    const float* __restrict__ w1, const float* __restrict__ mask,
    _Float16* __restrict__ W0, _Float16* __restrict__ W1) {
    const int n = blockIdx.x;
    const int k = threadIdx.x * 4;
    if (k >= KPAD) return;
    float4 e = {0.f, 0.f, 0.f, 0.f};
    if (k < INDIM) {
        float4 wv = *(const float4*)(w1 + (size_t)n * INDIM + k);
        float4 mv = *(const float4*)(mask + (size_t)n * INDIM + k);
        e.x = wv.x * mv.x; e.y = wv.y * mv.y;
        e.z = wv.z * mv.z; e.w = wv.w * mv.w;
    }
    f16x4 h, l;
    h[0] = (_Float16)e.x; l[0] = (_Float16)(e.x - (float)h[0]);
    h[1] = (_Float16)e.y; l[1] = (_Float16)(e.y - (float)h[1]);
    h[2] = (_Float16)e.z; l[2] = (_Float16)(e.z - (float)h[2]);
    h[3] = (_Float16)e.w; l[3] = (_Float16)(e.w - (float)h[3]);
    *(f16x4*)(W0 + (size_t)n * KPAD + k) = h;
    *(f16x4*)(W1 + (size_t)n * KPAD + k) = l;
}

// ---------------------------------------------------------------------------
// Kernel 2: MFMA GEMM, 32x32x16 f16, single-barrier-per-chunk pipeline.
// C tile 256x256, 512 thr = 8 waves (2M x 4N), per-wave 128x64 output
// (4 m-blocks x 2 n-blocks of 32x32).
// K' = 2112 = 66 chunks of 32 (3 segments x 22): X0*W0 + X0*W1 + X1*W0.
// LDS ring of 4 chunk-slots (A 16KB + B 16KB each) = 128 KB dynamic.
// Per chunk: {stage slot j+3 (4 gload_lds); 12 ds_read_b128; 16 MFMA
// (compiler-interleaved lgkmcnt); s_waitcnt vmcnt(8); barrier}.
// XOR swizzle both-sides (rule #21): physical [128 prow][8 x 16B],
// piece p = ((r&1)*4+c) ^ (pr&7); staged via pre-swizzled GLOBAL source.
// ---------------------------------------------------------------------------
__global__ __launch_bounds__(512, 1) void gemm_f16(
    const _Float16* __restrict__ X0, const _Float16* __restrict__ X1,
    const _Float16* __restrict__ W0, const _Float16* __restrict__ W1,
    const float* __restrict__ b1, float* __restrict__ C) {
    extern __shared__ char smem[];   // 131072 bytes: 4 slots x (16KB A + 16KB B)
    const int tid = threadIdx.x;
    const int w = tid >> 6, lane = tid & 63;
    const int wm = w >> 2, wn = w & 3;           // wave: 2M x 4N
    const int lr = lane & 31, cl = lane >> 5;    // frag row / k-half

    // XCD-aware swizzle (bijective: nwg = 8*tc, nwg%8==0)
    const int nwg = gridDim.x;
    const int cpx = nwg >> 3;
    const int o = blockIdx.x;
    const int wg = (o & 7) * cpx + (o >> 3);
    const int n0 = (wg & 7) * 256;
    const int m0 = (wg >> 3) * 256;

    // ---- staging precompute: physical (pr,p) -> logical (row rr, piece c),
    //      global byte offset (pre-swizzled source) ----
    size_t grA[2], grB[2];
#pragma unroll
    for (int i = 0; i < 2; ++i) {
        int pr = i * 64 + (tid >> 3);
        int p = tid & 7;
        int l = p ^ (pr & 7);
        int rr = 2 * pr + (l >> 2);
        int c = l & 3;
        grA[i] = (size_t)(m0 + rr) * (KPAD * 2) + (size_t)c * 16;
        grB[i] = (size_t)(n0 + rr) * (KPAD * 2) + (size_t)c * 16;
    }

    // ---- read-offset precompute (same involution); 32x32 frag:
    //      row = base + (lane&31), piece c = ks*2 + (lane>>5) ----
    int aoff[4][2], boff[2][2];
#pragma unroll
    for (int mb = 0; mb < 4; ++mb)
#pragma unroll
        for (int ks = 0; ks < 2; ++ks) {
            int row = wm * 128 + mb * 32 + lr;
            int c = ks * 2 + cl;
            int pr = row >> 1, l = (row & 1) * 4 + c, p = l ^ (pr & 7);
            aoff[mb][ks] = pr * 128 + p * 16;
        }
#pragma unroll
    for (int nb = 0; nb < 2; ++nb)
#pragma unroll
        for (int ks = 0; ks < 2; ++ks) {
            int row = wn * 64 + nb * 32 + lr;
            int c = ks * 2 + cl;
            int pr = row >> 1, l = (row & 1) * 4 + c, p = l ^ (pr & 7);
            boff[nb][ks] = pr * 128 + p * 16;
        }

    auto stageA = [&](int js) {
        int seg = (js >= 44) ? 2 : (js >= 22 ? 1 : 0);
        const char* base = (const char*)((seg < 2) ? X0 : X1);
        size_t ko = (size_t)(js - seg * 22) * 64;
        char* l0 = smem + (js & 3) * 32768 + w * 1024;
        gload_lds16(base + grA[0] + ko, l0);
        gload_lds16(base + grA[1] + ko, l0 + 8192);
    };
    auto stageB = [&](int js) {
        int seg = (js >= 44) ? 2 : (js >= 22 ? 1 : 0);
        const char* base = (const char*)((seg == 1) ? W1 : W0);
        size_t ko = (size_t)(js - seg * 22) * 64;
        char* l0 = smem + (js & 3) * 32768 + 16384 + w * 1024;
        gload_lds16(base + grB[0] + ko, l0);
        gload_lds16(base + grB[1] + ko, l0 + 8192);
    };

    f32x16 acc[4][2];
#pragma unroll
    for (int mb = 0; mb < 4; ++mb)
#pragma unroll
        for (int nb = 0; nb < 2; ++nb)
#pragma unroll
            for (int r = 0; r < 16; ++r) acc[mb][nb][r] = 0.f;

    // prologue: stage chunks 0,1,2 (12 loads/wave); chunk 0 ready -> vmcnt(8)
    stageA(0); stageB(0); stageA(1); stageB(1); stageA(2); stageB(2);
    asm volatile("s_waitcnt vmcnt(8)" ::: "memory");
    __builtin_amdgcn_s_barrier();
    __builtin_amdgcn_sched_barrier(0);

    for (int j = 0; j < NCHUNK; ++j) {
        const char* sa = smem + (j & 3) * 32768;
        const char* sb = sa + 16384;
        if (j + 3 < NCHUNK) { stageA(j + 3); stageB(j + 3); }
        f16x8 af[4][2], bf[2][2];
#pragma unroll
        for (int mb = 0; mb < 4; ++mb)
#pragma unroll
            for (int ks = 0; ks < 2; ++ks)
                af[mb][ks] = *(const f16x8*)(sa + aoff[mb][ks]);
#pragma unroll
        for (int nb = 0; nb < 2; ++nb)
#pragma unroll
            for (int ks = 0; ks < 2; ++ks)
                bf[nb][ks] = *(const f16x8*)(sb + boff[nb][ks]);
        __builtin_amdgcn_s_setprio(1);
#pragma unroll
        for (int ks = 0; ks < 2; ++ks)
#pragma unroll
            for (int mb = 0; mb < 4; ++mb)
#pragma unroll
                for (int nb = 0; nb < 2; ++nb)
                    acc[mb][nb] = __builtin_amdgcn_mfma_f32_32x32x16_f16(
                        af[mb][ks], bf[nb][ks], acc[mb][nb], 0, 0, 0);
        __builtin_amdgcn_s_setprio(0);
        if (j < NCHUNK - 3)
            asm volatile("s_waitcnt vmcnt(8)" ::: "memory");
        else if (j == NCHUNK - 3)
            asm volatile("s_waitcnt vmcnt(4)" ::: "memory");
        else
            asm volatile("s_waitcnt vmcnt(0)" ::: "memory");
        __builtin_amdgcn_s_barrier();
        __builtin_amdgcn_sched_barrier(0);
    }

    // epilogue: 32x32 C/D layout col=lane&31, row=(reg&3)+8*(reg>>2)+4*(lane>>5)
    const int rbase = m0 + wm * 128 + 4 * cl;
    const int col0 = n0 + wn * 64 + lr;
#pragma unroll
    for (int nb = 0; nb < 2; ++nb) {
        const int col = col0 + nb * 32;
        const float bias = b1[col];
#pragma unroll
        for (int mb = 0; mb < 4; ++mb) {
            f32x16 v = acc[mb][nb];
#pragma unroll
            for (int r = 0; r < 16; ++r) {
                int row = rbase + mb * 32 + (r & 3) + 8 * (r >> 2);
                C[(size_t)row * HK + col] = v[r] + bias;
            }
        }
    }
}

// ---------------------------------------------------------------------------
// Kernel 3: sequential SNN scan. Block = (batch, half); thread owns ONE
// neuron h = half*256 + tid (4 branches in registers). 512 blocks for TLP.
// ---------------------------------------------------------------------------
__global__ __launch_bounds__(256) void snn_scan(
    const float* __restrict__ Cur,         // (256, tc, 2048)
    const float* __restrict__ tau_m1,      // (512)
    const float* __restrict__ tau_n1,      // (512,4)
    float* __restrict__ st_d,              // (256,2048)
    float* __restrict__ st_m1,             // (256,512)
    unsigned long long* __restrict__ spk,  // (256,250,8)
    int t0, int tc) {
    const int b = blockIdx.x;
    const int half = blockIdx.y;
    const int tid = threadIdx.x;
    const int h = half * 256 + tid;
    const int wid = half * 4 + (tid >> 6), lane = tid & 63;
    const int coff = half * 1024 + tid * 4;

    const float a0 = sigf(tau_m1[h]);
    const float oma0 = 1.0f - a0;
    float4 tb = *(const float4*)(tau_n1 + h * 4);
    float be[4] = {sigf(tb.x), sigf(tb.y), sigf(tb.z), sigf(tb.w)};
    float ob[4] = {1.0f - be[0], 1.0f - be[1], 1.0f - be[2], 1.0f - be[3]};

    float d[4], m1, s;
    if (t0 == 0) {
        d[0] = d[1] = d[2] = d[3] = 0.0f;
        m1 = 0.0f; s = 0.0f;
    } else {
        float4 dv = *(const float4*)(st_d + (size_t)b * HK + coff);
        d[0] = dv.x; d[1] = dv.y; d[2] = dv.z; d[3] = dv.w;
        m1 = st_m1[(size_t)b * HID + h];
        const unsigned long long* sp = spk + ((size_t)b * TSTEPS + (t0 - 1)) * 8;
        s = ((sp[wid] >> lane) & 1ull) ? 1.0f : 0.0f;
    }

    const float* cbase = Cur + (size_t)b * tc * HK;
    float4 c0 = *(const float4*)(cbase + coff);

    for (int tt = 0; tt < tc; ++tt) {
        float4 nv;
        if (tt + 1 < tc)
            nv = *(const float4*)(cbase + (size_t)(tt + 1) * HK + coff);
        else
            nv = c0;

        d[0] = be[0] * d[0] + ob[0] * c0.x;
        d[1] = be[1] * d[1] + ob[1] * c0.y;
        d[2] = be[2] * d[2] + ob[2] * c0.z;
        d[3] = be[3] * d[3] + ob[3] * c0.w;
        float l = (d[0] + d[1]) + (d[2] + d[3]);

        m1 = a0 * m1 + oma0 * l - s;
        bool sp0 = m1 > 1.0f;
        s = sp0 ? 1.0f : 0.0f;

        unsigned long long mk = __ballot(sp0);
        if (lane == 0)
            spk[((size_t)b * TSTEPS + (t0 + tt)) * 8 + wid] = mk;
        c0 = nv;
    }

    float4 dv = {d[0], d[1], d[2], d[3]};
    *(float4*)(st_d + (size_t)b * HK + coff) = dv;
    st_m1[(size_t)b * HID + h] = m1;
}

// ---------------------------------------------------------------------------
// Kernel 4: out(b,t,o) = b2(o) + sum_h spk(b,t,h)*w2(o,h), bit-sparse.
// ---------------------------------------------------------------------------
__global__ __launch_bounds__(256) void spk_gemm(
    const unsigned long long* __restrict__ spk,  // (256,250,8)
    const float* __restrict__ w2,                // (20,512)
    const float* __restrict__ b2,                // (20)
    float* __restrict__ Y) {                     // (256,250,20)
    __shared__ float w2t[512][21];
    const int t = blockIdx.x;
    const int b = threadIdx.x;
    for (int i = threadIdx.x; i < HID * NOUT; i += 256) {
        int o = i / HID;
        int h = i - o * HID;
        w2t[h][o] = w2[i];
    }
    __syncthreads();
    float acc[NOUT];
#pragma unroll
    for (int o = 0; o < NOUT; ++o) acc[o] = b2[o];
    const unsigned long long* sp = spk + ((size_t)b * TSTEPS + t) * 8;
#pragma unroll
    for (int w = 0; w < 8; ++w) {
        unsigned long long m = sp[w];
        while (m) {
            int i = __ffsll((long long)m) - 1;
            m &= m - 1;
            const float* col = &w2t[w * 64 + i][0];
#pragma unroll
            for (int o = 0; o < NOUT; ++o) acc[o] += col[o];
        }
    }
    float* outp = Y + ((size_t)b * TSTEPS + t) * NOUT;
#pragma unroll
    for (int o = 0; o < NOUT; ++o) outp[o] = acc[o];
}

// ---------------------------------------------------------------------------
// Kernel 5a/5b/5c: chunked-parallel leaky readout filter (10 chunks of 25).
// Exact in real arithmetic (linearity); fp reorder error ~1e-7 on final out.
// ---------------------------------------------------------------------------
__global__ __launch_bounds__(256) void filter_part(
    float* __restrict__ Y, const float* __restrict__ tau_m2,
    float* __restrict__ fin) {
    int id = blockIdx.x * 256 + threadIdx.x;       // id = c*5120 + b*20 + o
    if (id >= BATCH * NOUT * FCH) return;
    int c = id / (BATCH * NOUT);
    int rem = id - c * (BATCH * NOUT);
    int b = rem / NOUT, o = rem - b * NOUT;
    float a2 = sigf(tau_m2[o]);
    float oma = 1.0f - a2;
    float m = 0.0f;
    float* p = Y + ((size_t)b * TSTEPS + c * FCL) * NOUT + o;
    for (int tt = 0; tt < FCL; ++tt) {
        m = a2 * m + oma * p[(size_t)tt * NOUT];
        p[(size_t)tt * NOUT] = m;
    }
    fin[id] = m;
}

__global__ __launch_bounds__(256) void filter_comb(
    const float* __restrict__ tau_m2, float* __restrict__ fin) {
    int id = blockIdx.x * 256 + threadIdx.x;       // (b,o)
    if (id >= BATCH * NOUT) return;
    int o = id % NOUT;
    float a2 = sigf(tau_m2[o]);
    float aL = powf(a2, (float)FCL);
    float m = 0.0f;
    for (int c = 0; c < FCH; ++c) {
        float f = fin[(size_t)c * (BATCH * NOUT) + id];
        fin[(size_t)c * (BATCH * NOUT) + id] = m;  // incoming state of chunk c
        m = aL * m + f;
    }
}

__global__ __launch_bounds__(256) void filter_fix(
    float* __restrict__ Y, const float* __restrict__ tau_m2,
    const float* __restrict__ fin) {
    int id = blockIdx.x * 256 + threadIdx.x;       // flat (b,t,o)
    if (id >= BATCH * TSTEPS * NOUT) return;
    int o = id % NOUT;
    int bt = id / NOUT;
    int t = bt % TSTEPS, b = bt / TSTEPS;
    int c = t / FCL, tt = t - c * FCL;
    float a2 = sigf(tau_m2[o]);
    float m0 = fin[(size_t)c * (BATCH * NOUT) + b * NOUT + o];
    if (m0 != 0.0f)
        Y[id] += powf(a2, (float)(tt + 1)) * m0;
}

// ---------------------------------------------------------------------------
extern "C" void kernel_launch(void* const* d_in, const int* in_sizes, int n_in,
                              void* d_out, int out_size, void* d_ws, size_t ws_size,
                              hipStream_t stream) {
    const float* x      = (const float*)d_in[0];
    const float* w1     = (const float*)d_in[1];
    const float* b1     = (const float*)d_in[2];
    const float* tau_m1 = (const float*)d_in[3];
    const float* tau_n1 = (const float*)d_in[4];
    const float* mask   = (const float*)d_in[5];
    const float* w2     = (const float*)d_in[6];
    const float* b2     = (const float*)d_in[7];
    const float* tau_m2 = (const float*)d_in[8];
    float* out = (float*)d_out;

    char* ws = (char*)d_ws;
    size_t off = 0;
    auto walloc = [&](size_t bytes) -> void* {
        void* p = ws + off;
        off += (bytes + 255) & ~(size_t)255;
        return p;
    };
    _Float16* W0 = (_Float16*)walloc((size_t)HK * KPAD * 2);          // 2.88 MB
    _Float16* W1 = (_Float16*)walloc((size_t)HK * KPAD * 2);          // 2.88 MB
    unsigned long long* spk =
        (unsigned long long*)walloc((size_t)BATCH * TSTEPS * 8 * 8);  // 4.10 MB
    float* st_d  = (float*)walloc((size_t)BATCH * HK * 4);            // 2.10 MB
    float* st_m1 = (float*)walloc((size_t)BATCH * HID * 4);           // 0.52 MB
    float* fin   = (float*)walloc((size_t)BATCH * NOUT * FCH * 4);    // 0.20 MB

    // per-timestep: cur (fp32) + X0 + X1 (fp16)
    const size_t perT = (size_t)BATCH * HK * 4 + 2 * (size_t)BATCH * KPAD * 2;
    size_t avail = (ws_size > off + 4096) ? ws_size - off - 4096 : 0;
    int Tc = (int)(avail / perT);
    if (Tc > TSTEPS) Tc = TSTEPS;
    if (Tc < 1) Tc = 1;
    _Float16* X0 = (_Float16*)walloc((size_t)BATCH * Tc * KPAD * 2);
    _Float16* X1 = (_Float16*)walloc((size_t)BATCH * Tc * KPAD * 2);
    float* cur   = (float*)walloc((size_t)BATCH * Tc * HK * 4);

    split_w<<<HK, 192, 0, stream>>>(w1, mask, W0, W1);

    for (int t0 = 0; t0 < TSTEPS; t0 += Tc) {
        int tc = (TSTEPS - t0 < Tc) ? (TSTEPS - t0) : Tc;
        split_x<<<BATCH * tc, 192, 0, stream>>>(x, X0, X1, t0, tc);
        // 256x256 tiles: M = 256*tc, N = 2048 -> 8*tc workgroups
        dim3 grid(8 * tc);
        gemm_f16<<<grid, 512, 131072, stream>>>(X0, X1, W0, W1, b1, cur);
        dim3 sgrid(BATCH, 2);
        snn_scan<<<sgrid, 256, 0, stream>>>(cur, tau_m1, tau_n1, st_d, st_m1,
                                            spk, t0, tc);
    }
    spk_gemm<<<TSTEPS, 256, 0, stream>>>(spk, w2, b2, out);
    filter_part<<<(BATCH * NOUT * FCH + 255) / 256, 256, 0, stream>>>(out, tau_m2, fin);
    filter_comb<<<(BATCH * NOUT + 255) / 256, 256, 0, stream>>>(tau_m2, fin);
    filter_fix<<<(BATCH * TSTEPS * NOUT + 255) / 256, 256, 0, stream>>>(out, tau_m2, fin);
}